// Round 4
// baseline (860.565 us; speedup 1.0000x reference)
//
#include <hip/hip_runtime.h>
#include <hip/hip_bf16.h>
#include <math.h>

// ---- problem constants ----
static constexpr int LEN = 4096;   // H*W
static constexpr int HN  = 64;     // H
static constexpr int WN  = 64;     // W
static constexpr int NB  = 2;      // batch
static constexpr int DM  = 192;    // d_model
static constexpr int DIM = 384;    // d_inner
static constexpr int NST = 16;     // n_state
static constexpr int DTR = 12;     // dt_rank
static constexpr int KD  = 4;      // directions
static constexpr int NC  = 32;     // scan chunks
static constexpr int CHL = LEN / NC; // 128 elements per chunk

// ---------------------------------------------------------------------------
// copy x (B,64,L) into F (B,192,L) channels [0,64)
__global__ void k_copy_x(const float* __restrict__ x, float* __restrict__ F) {
    int i = blockIdx.x * 256 + threadIdx.x;          // B*64*L = 524288
    if (i >= NB * 64 * LEN) return;
    int b = i / (64 * LEN); int r = i - b * 64 * LEN;
    F[(size_t)b * DM * LEN + r] = x[i];
}

// ---------------------------------------------------------------------------
// direct conv3x3 SAME, OCPT output channels per thread, optional leaky relu
template<int OCPT>
__global__ void k_conv3(const float* __restrict__ in, int inBufC, int cin,
                        const float* __restrict__ w, const float* __restrict__ bias,
                        float* __restrict__ out, int outBufC, int co0,
                        float slope, int act)
{
    int b  = blockIdx.z;
    int og = blockIdx.y;                              // oc group
    int y0 = (blockIdx.x >> 2) << 4, x0 = (blockIdx.x & 3) << 4;
    int ty = threadIdx.x >> 4, tx = threadIdx.x & 15;
    int yy = y0 + ty, xx = x0 + tx;

    float acc[OCPT];
#pragma unroll
    for (int o = 0; o < OCPT; ++o) acc[o] = bias[og * OCPT + o];

    for (int c = 0; c < cin; ++c) {
        const float* ip = in + ((size_t)(b * inBufC + c)) * LEN;
        const float* wp = w + ((size_t)(og * OCPT) * cin + c) * 9;
#pragma unroll
        for (int dy = 0; dy < 3; ++dy) {
            int iy = yy + dy - 1;
            bool oky = (unsigned)iy < (unsigned)HN;
#pragma unroll
            for (int dx = 0; dx < 3; ++dx) {
                int ix = xx + dx - 1;
                float v = (oky && (unsigned)ix < (unsigned)WN) ? ip[iy * WN + ix] : 0.f;
#pragma unroll
                for (int o = 0; o < OCPT; ++o)
                    acc[o] += v * wp[(size_t)o * cin * 9 + dy * 3 + dx];
            }
        }
    }
    size_t obase = ((size_t)(b * outBufC + co0 + og * OCPT)) * LEN + yy * WN + xx;
#pragma unroll
    for (int o = 0; o < OCPT; ++o) {
        float v = acc[o];
        if (act) v = v > 0.f ? v : v * slope;
        out[obase + (size_t)o * LEN] = v;
    }
}

// ---------------------------------------------------------------------------
// LayerNorm over 192 channels of planar F -> xn (B*L, 192) NHWC
__global__ void k_ln(const float* __restrict__ F, const float* __restrict__ g,
                     const float* __restrict__ be, float* __restrict__ xn)
{
    int lane = threadIdx.x & 63;
    int pix  = (blockIdx.x << 2) + (threadIdx.x >> 6);  // B*L pixels, 4 per block
    int b = pix >> 12, l = pix & (LEN - 1);
    const float* fp = F + (size_t)b * DM * LEN + l;
    float v0 = fp[(size_t)lane * LEN];
    float v1 = fp[(size_t)(lane + 64) * LEN];
    float v2 = fp[(size_t)(lane + 128) * LEN];
    float s = v0 + v1 + v2, ss = v0 * v0 + v1 * v1 + v2 * v2;
#pragma unroll
    for (int off = 1; off < 64; off <<= 1) { s += __shfl_xor(s, off); ss += __shfl_xor(ss, off); }
    float mu = s * (1.f / 192.f);
    float var = ss * (1.f / 192.f) - mu * mu;
    float rstd = rsqrtf(var + 1e-5f);
    float* op = xn + (size_t)pix * DM;
    op[lane]       = (v0 - mu) * rstd * g[lane]       + be[lane];
    op[lane + 64]  = (v1 - mu) * rstd * g[lane + 64]  + be[lane + 64];
    op[lane + 128] = (v2 - mu) * rstd * g[lane + 128] + be[lane + 128];
}

// ---------------------------------------------------------------------------
// tiled f32 GEMM: A (B*L, K) NHWC  x  Wt (N, K)  ->  Cp planar (B, outC, L)
// optional residual (planar, same layout as Cp) added.
__global__ void __launch_bounds__(256) k_gemm(
    const float* __restrict__ A, int K,
    const float* __restrict__ Wt,
    const float* __restrict__ res,
    float* __restrict__ Cp, int outC)
{
    __shared__ float As[64][65];
    __shared__ float Bs[64][65];
    int b  = blockIdx.z;
    int l0 = blockIdx.x << 6, n0 = blockIdx.y << 6;
    int tid = threadIdx.x;
    int tl = (tid & 15) << 2, tn = (tid >> 4) << 2;
    float acc[4][4] = {};

    for (int k0 = 0; k0 < K; k0 += 64) {
#pragma unroll
        for (int s = 0; s < 4; ++s) {
            int e = (s << 10) + (tid << 2);
            int row = e >> 6, col = e & 63;
            float4 av = *(const float4*)(A + ((size_t)b * LEN + l0 + row) * K + k0 + col);
            As[row][col] = av.x; As[row][col + 1] = av.y; As[row][col + 2] = av.z; As[row][col + 3] = av.w;
            float4 wv = *(const float4*)(Wt + (size_t)(n0 + row) * K + k0 + col);
            Bs[row][col] = wv.x; Bs[row][col + 1] = wv.y; Bs[row][col + 2] = wv.z; Bs[row][col + 3] = wv.w;
        }
        __syncthreads();
#pragma unroll
        for (int kk = 0; kk < 64; ++kk) {
            float a0 = As[tl][kk], a1 = As[tl + 1][kk], a2 = As[tl + 2][kk], a3 = As[tl + 3][kk];
            float b0 = Bs[tn][kk], b1 = Bs[tn + 1][kk], b2 = Bs[tn + 2][kk], b3 = Bs[tn + 3][kk];
            acc[0][0] += a0 * b0; acc[0][1] += a0 * b1; acc[0][2] += a0 * b2; acc[0][3] += a0 * b3;
            acc[1][0] += a1 * b0; acc[1][1] += a1 * b1; acc[1][2] += a1 * b2; acc[1][3] += a1 * b3;
            acc[2][0] += a2 * b0; acc[2][1] += a2 * b1; acc[2][2] += a2 * b2; acc[2][3] += a2 * b3;
            acc[3][0] += a3 * b0; acc[3][1] += a3 * b1; acc[3][2] += a3 * b2; acc[3][3] += a3 * b3;
        }
        __syncthreads();
    }
#pragma unroll
    for (int j = 0; j < 4; ++j) {
        size_t o = ((size_t)(b * outC) + n0 + tn + j) * LEN + l0 + tl;
        float4 v;
        v.x = acc[0][j]; v.y = acc[1][j]; v.z = acc[2][j]; v.w = acc[3][j];
        if (res) {
            float4 r = *(const float4*)(res + o);
            v.x += r.x; v.y += r.y; v.z += r.z; v.w += r.w;
        }
        *(float4*)(Cp + o) = v;
    }
}

// ---------------------------------------------------------------------------
// depthwise conv3x3 + SiLU : xz channels [0,384) -> xc (B,384,L)
__global__ void k_dw(const float* __restrict__ xz, const float* __restrict__ w,
                     const float* __restrict__ bias, float* __restrict__ xc)
{
    int i = blockIdx.x * 256 + threadIdx.x;           // B*384*L
    if (i >= NB * DIM * LEN) return;
    int l = i & (LEN - 1); int bc = i >> 12; int c = bc % DIM; int b = bc / DIM;
    int y = l >> 6, x = l & 63;
    const float* ip = xz + ((size_t)(b * 2 * DIM + c)) * LEN;
    const float* wp = w + c * 9;
    float acc = bias[c];
#pragma unroll
    for (int dy = 0; dy < 3; ++dy) {
        int iy = y + dy - 1;
        if ((unsigned)iy >= (unsigned)HN) continue;
#pragma unroll
        for (int dx = 0; dx < 3; ++dx) {
            int ix = x + dx - 1;
            if ((unsigned)ix >= (unsigned)WN) continue;
            acc += ip[iy * WN + ix] * wp[dy * 3 + dx];
        }
    }
    acc = acc / (1.f + expf(-acc));                   // silu
    xc[((size_t)(b * DIM + c)) * LEN + l] = acc;
}

// ---------------------------------------------------------------------------
// per-plane 64x64 transpose: xct[b,c, w*64+h] = xc[b,c, h*64+w]
__global__ void k_tr(const float* __restrict__ xc, float* __restrict__ xct)
{
    __shared__ float t[64][65];
    int bc = blockIdx.x;                              // B*384
    const float* ip = xc + (size_t)bc * LEN;
    float* op = xct + (size_t)bc * LEN;
    int col = threadIdx.x & 63, rq = threadIdx.x >> 6;
#pragma unroll
    for (int r = 0; r < 64; r += 4) t[r + rq][col] = ip[(r + rq) * 64 + col];
    __syncthreads();
#pragma unroll
    for (int r = 0; r < 64; r += 4) op[(r + rq) * 64 + col] = t[col][r + rq];
}

// ---------------------------------------------------------------------------
// fused x_proj + dt GEMV + softplus.
// per block: 64 pixels of one (b,k). LDS-staged 64x64 src tiles (6 of them),
// 11 output channels per wave (44 = 4 waves x 11).
// outputs: bcb (B,4,L,32) = [B rows | C rows] coalesced; delta (B,4,384,L).
__global__ void __launch_bounds__(256) k_xdbl_delta(
    const float* __restrict__ xc, const float* __restrict__ xct,
    const float* __restrict__ xpw, const float* __restrict__ dtw,
    const float* __restrict__ dtb, float* __restrict__ bcb,
    float* __restrict__ delta)
{
    __shared__ float xs[64][68];
    int b = blockIdx.z, k = blockIdx.y;
    int l0 = blockIdx.x << 6;
    int tid = threadIdx.x;
    int lane = tid & 63, wv = tid >> 6;
    bool rev = (k & 2) != 0;
    int basecol = rev ? (LEN - 64 - l0) : l0;
    const float* src = ((k & 1) ? xct : xc) + (size_t)b * DIM * LEN + basecol;
    int lcol = rev ? (63 - lane) : lane;
    const float* wp = xpw + (size_t)k * 44 * DIM;
    int c0 = wv * 11;
    float acc[11] = {};

    for (int d0 = 0; d0 < DIM; d0 += 64) {
#pragma unroll
        for (int i = 0; i < 4; ++i) {
            int idx = (i << 8) + tid;                 // 0..1023
            int row = idx >> 4, col = (idx & 15) << 2;
            float4 v = *(const float4*)(src + (size_t)(d0 + row) * LEN + col);
            xs[row][col] = v.x; xs[row][col + 1] = v.y;
            xs[row][col + 2] = v.z; xs[row][col + 3] = v.w;
        }
        __syncthreads();
#pragma unroll 4
        for (int d = 0; d < 64; ++d) {
            float u = xs[d][lcol];
            const float* wd = wp + (size_t)c0 * DIM + d0 + d;
#pragma unroll
            for (int j = 0; j < 11; ++j)
                acc[j] += u * wd[(size_t)j * DIM];
        }
        __syncthreads();
    }

    // park all 44 outputs in LDS: xs[c][l]
#pragma unroll
    for (int j = 0; j < 11; ++j) xs[c0 + j][lane] = acc[j];
    __syncthreads();

    // coalesced B/C store: bcb[(b,k,l), c] c in [0,32) = x_dbl[12+c]
    float* op = bcb + ((size_t)((b * KD + k) * LEN) + l0) * 32;
#pragma unroll
    for (int i = 0; i < 8; ++i) {
        int idx = (i << 8) + tid;                     // 0..2047
        int l = idx >> 5, c = idx & 31;
        op[idx] = xs[12 + c][l];
    }

    // delta: softplus(dtb + sum_r xs[r][lane] * dtw[d][r]) for all 384 d
    for (int d = wv; d < DIM; d += 4) {
        const float* wpd = dtw + ((size_t)(k * DIM + d)) * DTR;
        float s = dtb[k * DIM + d];
#pragma unroll
        for (int r = 0; r < DTR; ++r) s += xs[r][lane] * wpd[r];
        s = (s > 20.f) ? s : __logf(1.f + __expf(s));
        delta[((size_t)((b * KD + k) * DIM) + d) * LEN + l0 + lane] = s;
    }
}

// ---------------------------------------------------------------------------
// chunked selective scan, phase A. thread = d; all 16 states in registers.
// B staged in LDS (uniform broadcast reads). h,p written per chunk.
__global__ void __launch_bounds__(384) k_scan_a(
    const float* __restrict__ xc, const float* __restrict__ xct,
    const float* __restrict__ bcb, const float* __restrict__ alog,
    const float* __restrict__ dlt, float* __restrict__ hf, float* __restrict__ pA)
{
    __shared__ float bs[CHL * 16];
    int b = blockIdx.z, k = blockIdx.y, c = blockIdx.x;
    int d = threadIdx.x;
    const float* bc = bcb + ((size_t)((b * KD + k) * LEN) + c * CHL) * 32;
    // stage B (cols 0..15 of each 32-float row)
    for (int i = threadIdx.x; i < CHL * 4; i += 384) {
        int l = i >> 2, q = i & 3;
        ((float4*)bs)[i] = ((const float4*)bc)[l * 8 + q];
    }
    __syncthreads();

    float A[16], h[16], p[16];
    const float* ap = alog + ((size_t)(k * DIM + d)) * NST;
#pragma unroll
    for (int q = 0; q < 4; ++q) {
        float4 av = *(const float4*)(ap + q * 4);
        A[q * 4]     = -__expf(av.x); A[q * 4 + 1] = -__expf(av.y);
        A[q * 4 + 2] = -__expf(av.z); A[q * 4 + 3] = -__expf(av.w);
    }
#pragma unroll
    for (int n = 0; n < 16; ++n) { h[n] = 0.f; p[n] = 1.f; }

    const float* up = ((k & 1) ? xct : xc) + ((size_t)(b * DIM + d)) * LEN;
    const float* dp = dlt + ((size_t)((b * KD + k) * DIM) + d) * LEN + c * CHL;
    bool rev = (k & 2) != 0;

    for (int l0 = 0; l0 < CHL; l0 += 4) {
        float dv[4], uu[4];
        *(float4*)dv = *(const float4*)(dp + l0);
        int g0 = c * CHL + l0;
        float ut[4];
        if (rev) {
            *(float4*)ut = *(const float4*)(up + (LEN - 4 - g0));
            uu[0] = ut[3]; uu[1] = ut[2]; uu[2] = ut[1]; uu[3] = ut[0];
        } else {
            *(float4*)ut = *(const float4*)(up + g0);
            uu[0] = ut[0]; uu[1] = ut[1]; uu[2] = ut[2]; uu[3] = ut[3];
        }
#pragma unroll
        for (int j = 0; j < 4; ++j) {
            float Bv[16];
#pragma unroll
            for (int q = 0; q < 4; ++q)
                *(float4*)(Bv + q * 4) = ((const float4*)bs)[(l0 + j) * 4 + q];
            float du = dv[j] * uu[j];
#pragma unroll
            for (int n = 0; n < 16; ++n) {
                float dA = __expf(dv[j] * A[n]);
                h[n] = dA * h[n] + du * Bv[n];
                p[n] *= dA;
            }
        }
    }
    size_t s0 = (((size_t)((b * KD + k) * DIM) + d) * NST) * NC + c;
#pragma unroll
    for (int n = 0; n < 16; ++n) { hf[s0 + (size_t)n * NC] = h[n]; pA[s0 + (size_t)n * NC] = p[n]; }
}

// phase B: serial carry combine over chunks; hf[c] overwritten with carry-IN.
__global__ void k_scan_b(float* __restrict__ hf, const float* __restrict__ pA)
{
    int s = blockIdx.x * 256 + threadIdx.x;          // 49152 states
    float* hp = hf + (size_t)s * NC;
    const float* pp = pA + (size_t)s * NC;
    float car = 0.f;
#pragma unroll
    for (int c = 0; c < NC; ++c) {
        float hfc = hp[c], pc = pp[c];
        hp[c] = car;
        car = pc * car + hfc;
    }
}

// phase C: re-run chunk from carry-in, y in-register (no shuffles), write y over delta.
__global__ void __launch_bounds__(384) k_scan_c(
    const float* __restrict__ xc, const float* __restrict__ xct,
    const float* __restrict__ bcb, const float* __restrict__ alog,
    const float* __restrict__ hf, float* __restrict__ dlt)
{
    __shared__ float bs[CHL * 32];
    int b = blockIdx.z, k = blockIdx.y, c = blockIdx.x;
    int d = threadIdx.x;
    const float* bc = bcb + ((size_t)((b * KD + k) * LEN) + c * CHL) * 32;
    for (int i = threadIdx.x; i < CHL * 8; i += 384)
        ((float4*)bs)[i] = ((const float4*)bc)[i];
    __syncthreads();

    float A[16], h[16];
    const float* ap = alog + ((size_t)(k * DIM + d)) * NST;
#pragma unroll
    for (int q = 0; q < 4; ++q) {
        float4 av = *(const float4*)(ap + q * 4);
        A[q * 4]     = -__expf(av.x); A[q * 4 + 1] = -__expf(av.y);
        A[q * 4 + 2] = -__expf(av.z); A[q * 4 + 3] = -__expf(av.w);
    }
    size_t s0 = (((size_t)((b * KD + k) * DIM) + d) * NST) * NC + c;
#pragma unroll
    for (int n = 0; n < 16; ++n) h[n] = hf[s0 + (size_t)n * NC];

    const float* up = ((k & 1) ? xct : xc) + ((size_t)(b * DIM + d)) * LEN;
    float* dp = dlt + ((size_t)((b * KD + k) * DIM) + d) * LEN + c * CHL;
    bool rev = (k & 2) != 0;

    for (int l0 = 0; l0 < CHL; l0 += 4) {
        float dv[4], uu[4];
        *(float4*)dv = *(const float4*)(dp + l0);
        int g0 = c * CHL + l0;
        float ut[4];
        if (rev) {
            *(float4*)ut = *(const float4*)(up + (LEN - 4 - g0));
            uu[0] = ut[3]; uu[1] = ut[2]; uu[2] = ut[1]; uu[3] = ut[0];
        } else {
            *(float4*)ut = *(const float4*)(up + g0);
            uu[0] = ut[0]; uu[1] = ut[1]; uu[2] = ut[2]; uu[3] = ut[3];
        }
        float ys[4];
#pragma unroll
        for (int j = 0; j < 4; ++j) {
            float Bv[16], Cv[16];
#pragma unroll
            for (int q = 0; q < 4; ++q) {
                *(float4*)(Bv + q * 4) = ((const float4*)bs)[(l0 + j) * 8 + q];
                *(float4*)(Cv + q * 4) = ((const float4*)bs)[(l0 + j) * 8 + 4 + q];
            }
            float du = dv[j] * uu[j];
            float y = 0.f;
#pragma unroll
            for (int n = 0; n < 16; ++n) {
                float dA = __expf(dv[j] * A[n]);
                h[n] = dA * h[n] + du * Bv[n];
                y += h[n] * Cv[n];
            }
            ys[j] = y;
        }
        *(float4*)(dp + l0) = *(const float4*)ys;
    }
}

// ---------------------------------------------------------------------------
// merge 4 directions + D*u + out-LN + silu(z) gate -> yg (B*L, 384) NHWC
__global__ void k_merge(const float* __restrict__ y4, const float* __restrict__ xc,
                        const float* __restrict__ Ds, const float* __restrict__ ong,
                        const float* __restrict__ onb, const float* __restrict__ xz,
                        float* __restrict__ yg)
{
    int lane = threadIdx.x & 63;
    int pix = (blockIdx.x << 2) + (threadIdx.x >> 6);
    int b = pix >> 12, l = pix & (LEN - 1);
    int hh = l >> 6, ww = l & 63;
    int lt = (ww << 6) + hh;
    float v[6]; float s = 0.f, ss = 0.f;
#pragma unroll
    for (int j = 0; j < 6; ++j) {
        int d = lane + (j << 6);
        size_t base = ((size_t)(b * KD) * DIM + d) * LEN;
        float y = y4[base + l]
                + y4[base + (size_t)DIM * LEN + lt]
                + y4[base + (size_t)2 * DIM * LEN + (LEN - 1 - l)]
                + y4[base + (size_t)3 * DIM * LEN + (LEN - 1 - lt)];
        float dsum = Ds[d] + Ds[DIM + d] + Ds[2 * DIM + d] + Ds[3 * DIM + d];
        y += dsum * xc[((size_t)(b * DIM + d)) * LEN + l];
        v[j] = y; s += y; ss += y * y;
    }
#pragma unroll
    for (int off = 1; off < 64; off <<= 1) { s += __shfl_xor(s, off); ss += __shfl_xor(ss, off); }
    float mu = s * (1.f / 384.f);
    float var = ss * (1.f / 384.f) - mu * mu;
    float rstd = rsqrtf(var + 1e-5f);
    float* op = yg + (size_t)pix * DIM;
#pragma unroll
    for (int j = 0; j < 6; ++j) {
        int d = lane + (j << 6);
        float zz = xz[((size_t)(b * 2 * DIM) + DIM + d) * LEN + l];
        float gate = zz / (1.f + expf(-zz));
        op[d] = ((v[j] - mu) * rstd * ong[d] + onb[d]) * gate;
    }
}

// ---------------------------------------------------------------------------
extern "C" void kernel_launch(void* const* d_in, const int* in_sizes, int n_in,
                              void* d_out, int out_size, void* d_ws, size_t ws_size,
                              hipStream_t stream)
{
    const float* x    = (const float*)d_in[0];
    const float* c1w  = (const float*)d_in[1];  const float* c1b = (const float*)d_in[2];
    const float* c2w  = (const float*)d_in[3];  const float* c2b = (const float*)d_in[4];
    const float* c3w  = (const float*)d_in[5];  const float* c3b = (const float*)d_in[6];
    const float* c4w  = (const float*)d_in[7];  const float* c4b = (const float*)d_in[8];
    const float* c5w  = (const float*)d_in[9];  const float* c5b = (const float*)d_in[10];
    const float* ln1g = (const float*)d_in[11]; const float* ln1b= (const float*)d_in[12];
    const float* ipw  = (const float*)d_in[13];
    const float* dww  = (const float*)d_in[14]; const float* dwb = (const float*)d_in[15];
    const float* xpw  = (const float*)d_in[16];
    const float* dtw  = (const float*)d_in[17]; const float* dtb = (const float*)d_in[18];
    const float* alog = (const float*)d_in[19]; const float* dsv = (const float*)d_in[20];
    const float* ong  = (const float*)d_in[21]; const float* onb = (const float*)d_in[22];
    const float* opw  = (const float*)d_in[23];
    float* out = (float*)d_out;

    float* ws   = (float*)d_ws;
    float* F    = ws;                   // (B,192,L)            1,572,864
    float* XN   = F    + 1572864;       // (B*L,192); HF during scan; later sa
    float* XZ   = XN   + 1572864;       // (B,768,L); b0-xp region = PA during scan
    float* XC   = XZ   + 6291456;       // (B,384,L)            3,145,728
    float* XCT  = XC   + 3145728;       // (B,384,L); later yg  3,145,728
    float* BCB  = XCT  + 3145728;       // (B,4,L,32)           1,048,576
    float* DLT  = BCB  + 1441792;       // (B,4,384,L) delta->y 12,582,912
    float* HF = XN;                     // 1,572,864 = NB*KD*DIM*NST*NC exactly
    float* PA = XZ;                     // 1,572,864 (b0 xp half, dead after k_dw)

    // stage A: dense conv block
    k_copy_x<<<dim3(2048), 256, 0, stream>>>(x, F);
    k_conv3<2><<<dim3(16, 16, NB), 256, 0, stream>>>(F, DM, 64,  c1w, c1b, F, DM, 64,  0.01f, 1);
    k_conv3<2><<<dim3(16, 16, NB), 256, 0, stream>>>(F, DM, 96,  c2w, c2b, F, DM, 96,  0.01f, 1);
    k_conv3<2><<<dim3(16, 16, NB), 256, 0, stream>>>(F, DM, 128, c3w, c3b, F, DM, 128, 0.01f, 1);
    k_conv3<2><<<dim3(16, 16, NB), 256, 0, stream>>>(F, DM, 160, c4w, c4b, F, DM, 160, 0.01f, 1);

    // stage B: VSS block
    k_ln<<<dim3(NB * LEN / 4), 256, 0, stream>>>(F, ln1g, ln1b, XN);
    k_gemm<<<dim3(LEN / 64, 768 / 64, NB), 256, 0, stream>>>(XN, DM, ipw, nullptr, XZ, 768);
    k_dw<<<dim3(NB * DIM * LEN / 256), 256, 0, stream>>>(XZ, dww, dwb, XC);
    k_tr<<<dim3(NB * DIM), 256, 0, stream>>>(XC, XCT);
    k_xdbl_delta<<<dim3(LEN / 64, KD, NB), 256, 0, stream>>>(XC, XCT, xpw, dtw, dtb, BCB, DLT);
    k_scan_a<<<dim3(NC, KD, NB), 384, 0, stream>>>(XC, XCT, BCB, alog, DLT, HF, PA);
    k_scan_b<<<dim3(NB * KD * DIM * NST / 256), 256, 0, stream>>>(HF, PA);
    k_scan_c<<<dim3(NC, KD, NB), 384, 0, stream>>>(XC, XCT, BCB, alog, HF, DLT);
    k_merge<<<dim3(NB * LEN / 4), 256, 0, stream>>>(DLT, XC, dsv, ong, onb, XZ, XCT);
    k_gemm<<<dim3(LEN / 64, DM / 64, NB), 256, 0, stream>>>(XCT, DIM, opw, F, XN, DM);

    // stage C: final conv
    k_conv3<4><<<dim3(16, 16, NB), 256, 0, stream>>>(XN, DM, DM, c5w, c5b, out, 64, 0, 0.f, 0);
}

// Round 5
// 721.646 us; speedup vs baseline: 1.1925x; 1.1925x over previous
//
#include <hip/hip_runtime.h>
#include <hip/hip_bf16.h>
#include <math.h>

// ---- problem constants ----
static constexpr int LEN = 4096;   // H*W
static constexpr int HN  = 64;     // H
static constexpr int WN  = 64;     // W
static constexpr int NB  = 2;      // batch
static constexpr int DM  = 192;    // d_model
static constexpr int DIM = 384;    // d_inner
static constexpr int NST = 16;     // n_state
static constexpr int DTR = 12;     // dt_rank
static constexpr int KD  = 4;      // directions
static constexpr int NC  = 32;     // scan chunks
static constexpr int CHL = LEN / NC; // 128 elements per chunk

// direction k seq-position -> pixel row index (uniform across a wave)
__device__ __forceinline__ int maprow(int k, int gl) {
    int g = (k & 2) ? (LEN - 1 - gl) : gl;
    return (k & 1) ? (((g & 63) << 6) | (g >> 6)) : g;
}

// ---------------------------------------------------------------------------
// copy x (B,64,L) into F (B,192,L) channels [0,64)
__global__ void k_copy_x(const float* __restrict__ x, float* __restrict__ F) {
    int i = blockIdx.x * 256 + threadIdx.x;          // B*64*L = 524288
    if (i >= NB * 64 * LEN) return;
    int b = i / (64 * LEN); int r = i - b * 64 * LEN;
    F[(size_t)b * DM * LEN + r] = x[i];
}

// ---------------------------------------------------------------------------
// direct conv3x3 SAME, OCPT output channels per thread, optional leaky relu
template<int OCPT>
__global__ void k_conv3(const float* __restrict__ in, int inBufC, int cin,
                        const float* __restrict__ w, const float* __restrict__ bias,
                        float* __restrict__ out, int outBufC, int co0,
                        float slope, int act)
{
    int b  = blockIdx.z;
    int og = blockIdx.y;                              // oc group
    int y0 = (blockIdx.x >> 2) << 4, x0 = (blockIdx.x & 3) << 4;
    int ty = threadIdx.x >> 4, tx = threadIdx.x & 15;
    int yy = y0 + ty, xx = x0 + tx;

    float acc[OCPT];
#pragma unroll
    for (int o = 0; o < OCPT; ++o) acc[o] = bias[og * OCPT + o];

    for (int c = 0; c < cin; ++c) {
        const float* ip = in + ((size_t)(b * inBufC + c)) * LEN;
        const float* wp = w + ((size_t)(og * OCPT) * cin + c) * 9;
#pragma unroll
        for (int dy = 0; dy < 3; ++dy) {
            int iy = yy + dy - 1;
            bool oky = (unsigned)iy < (unsigned)HN;
#pragma unroll
            for (int dx = 0; dx < 3; ++dx) {
                int ix = xx + dx - 1;
                float v = (oky && (unsigned)ix < (unsigned)WN) ? ip[iy * WN + ix] : 0.f;
#pragma unroll
                for (int o = 0; o < OCPT; ++o)
                    acc[o] += v * wp[(size_t)o * cin * 9 + dy * 3 + dx];
            }
        }
    }
    size_t obase = ((size_t)(b * outBufC + co0 + og * OCPT)) * LEN + yy * WN + xx;
#pragma unroll
    for (int o = 0; o < OCPT; ++o) {
        float v = acc[o];
        if (act) v = v > 0.f ? v : v * slope;
        out[obase + (size_t)o * LEN] = v;
    }
}

// ---------------------------------------------------------------------------
// LayerNorm over 192 channels of planar F -> xn (B*L, 192) NHWC
__global__ void k_ln(const float* __restrict__ F, const float* __restrict__ g,
                     const float* __restrict__ be, float* __restrict__ xn)
{
    int lane = threadIdx.x & 63;
    int pix  = (blockIdx.x << 2) + (threadIdx.x >> 6);  // B*L pixels, 4 per block
    int b = pix >> 12, l = pix & (LEN - 1);
    const float* fp = F + (size_t)b * DM * LEN + l;
    float v0 = fp[(size_t)lane * LEN];
    float v1 = fp[(size_t)(lane + 64) * LEN];
    float v2 = fp[(size_t)(lane + 128) * LEN];
    float s = v0 + v1 + v2, ss = v0 * v0 + v1 * v1 + v2 * v2;
#pragma unroll
    for (int off = 1; off < 64; off <<= 1) { s += __shfl_xor(s, off); ss += __shfl_xor(ss, off); }
    float mu = s * (1.f / 192.f);
    float var = ss * (1.f / 192.f) - mu * mu;
    float rstd = rsqrtf(var + 1e-5f);
    float* op = xn + (size_t)pix * DM;
    op[lane]       = (v0 - mu) * rstd * g[lane]       + be[lane];
    op[lane + 64]  = (v1 - mu) * rstd * g[lane + 64]  + be[lane + 64];
    op[lane + 128] = (v2 - mu) * rstd * g[lane + 128] + be[lane + 128];
}

// ---------------------------------------------------------------------------
// tiled f32 GEMM: A (B*L, K) NHWC  x  Wt (N, K)  ->  planar (B,outC,L) or NHWC
__global__ void __launch_bounds__(256) k_gemm(
    const float* __restrict__ A, int K,
    const float* __restrict__ Wt,
    const float* __restrict__ res,
    float* __restrict__ Cp, int outC, int nhwc)
{
    __shared__ float As[64][65];
    __shared__ float Bs[64][65];
    int b  = blockIdx.z;
    int l0 = blockIdx.x << 6, n0 = blockIdx.y << 6;
    int tid = threadIdx.x;
    int tl = (tid & 15) << 2, tn = (tid >> 4) << 2;
    float acc[4][4] = {};

    for (int k0 = 0; k0 < K; k0 += 64) {
#pragma unroll
        for (int s = 0; s < 4; ++s) {
            int e = (s << 10) + (tid << 2);
            int row = e >> 6, col = e & 63;
            float4 av = *(const float4*)(A + ((size_t)b * LEN + l0 + row) * K + k0 + col);
            As[row][col] = av.x; As[row][col + 1] = av.y; As[row][col + 2] = av.z; As[row][col + 3] = av.w;
            float4 wv = *(const float4*)(Wt + (size_t)(n0 + row) * K + k0 + col);
            Bs[row][col] = wv.x; Bs[row][col + 1] = wv.y; Bs[row][col + 2] = wv.z; Bs[row][col + 3] = wv.w;
        }
        __syncthreads();
#pragma unroll
        for (int kk = 0; kk < 64; ++kk) {
            float a0 = As[tl][kk], a1 = As[tl + 1][kk], a2 = As[tl + 2][kk], a3 = As[tl + 3][kk];
            float b0 = Bs[tn][kk], b1 = Bs[tn + 1][kk], b2 = Bs[tn + 2][kk], b3 = Bs[tn + 3][kk];
            acc[0][0] += a0 * b0; acc[0][1] += a0 * b1; acc[0][2] += a0 * b2; acc[0][3] += a0 * b3;
            acc[1][0] += a1 * b0; acc[1][1] += a1 * b1; acc[1][2] += a1 * b2; acc[1][3] += a1 * b3;
            acc[2][0] += a2 * b0; acc[2][1] += a2 * b1; acc[2][2] += a2 * b2; acc[2][3] += a2 * b3;
            acc[3][0] += a3 * b0; acc[3][1] += a3 * b1; acc[3][2] += a3 * b2; acc[3][3] += a3 * b3;
        }
        __syncthreads();
    }
    if (!nhwc) {
#pragma unroll
        for (int j = 0; j < 4; ++j) {
            size_t o = ((size_t)(b * outC) + n0 + tn + j) * LEN + l0 + tl;
            float4 v;
            v.x = acc[0][j]; v.y = acc[1][j]; v.z = acc[2][j]; v.w = acc[3][j];
            if (res) {
                float4 r = *(const float4*)(res + o);
                v.x += r.x; v.y += r.y; v.z += r.z; v.w += r.w;
            }
            *(float4*)(Cp + o) = v;
        }
    } else {
#pragma unroll
        for (int i = 0; i < 4; ++i) {
            size_t o = ((size_t)b * LEN + l0 + tl + i) * outC + n0 + tn;
            float4 v;
            v.x = acc[i][0]; v.y = acc[i][1]; v.z = acc[i][2]; v.w = acc[i][3];
            *(float4*)(Cp + o) = v;
        }
    }
}

// ---------------------------------------------------------------------------
// depthwise conv3x3 + SiLU : xp planar (B,384,L) -> unh NHWC (B*L, 384)
__global__ void __launch_bounds__(256) k_dw(
    const float* __restrict__ xp, const float* __restrict__ w,
    const float* __restrict__ bias, float* __restrict__ unh)
{
    __shared__ float t[64][65];
    int b = blockIdx.z, cg = blockIdx.y, r = blockIdx.x;  // r = spatial row
    int x = threadIdx.x & 63, cs = threadIdx.x >> 6;
#pragma unroll
    for (int i = 0; i < 16; ++i) {
        int c = cg * 64 + cs * 16 + i;
        const float* ip = xp + ((size_t)(b * DIM + c)) * LEN;
        const float* wp = w + c * 9;
        float acc = bias[c];
#pragma unroll
        for (int dy = 0; dy < 3; ++dy) {
            int ry = r + dy - 1;
            if ((unsigned)ry >= (unsigned)HN) continue;
#pragma unroll
            for (int dx = 0; dx < 3; ++dx) {
                int xx = x + dx - 1;
                if ((unsigned)xx >= (unsigned)WN) continue;
                acc += ip[ry * WN + xx] * wp[dy * 3 + dx];
            }
        }
        acc = acc / (1.f + __expf(-acc));
        t[x][cs * 16 + i] = acc;
    }
    __syncthreads();
    float* op = unh + ((size_t)b * LEN + r * 64) * DIM + cg * 64;
#pragma unroll
    for (int i = 0; i < 16; ++i) {
        int idx = (i << 8) + threadIdx.x;
        int px = idx >> 6, cc = idx & 63;
        op[(size_t)px * DIM + cc] = t[px][cc];
    }
}

// ---------------------------------------------------------------------------
// fused x_proj + dt GEMV + softplus, NHWC source.
// outputs: bcb (B,4,L,32) coalesced; delta NHWC (B,4,L,384).
__global__ void __launch_bounds__(256) k_xdbl_delta(
    const float* __restrict__ unh, const float* __restrict__ xpw,
    const float* __restrict__ dtw, const float* __restrict__ dtb,
    float* __restrict__ bcb, float* __restrict__ dlt)
{
    __shared__ float xs[64][65];
    __shared__ float ds2[64][65];
    int b = blockIdx.z, k = blockIdx.y;
    int l0 = blockIdx.x << 6;
    int tid = threadIdx.x;
    int lane = tid & 63, wv = tid >> 6;
    const float* ub = unh + (size_t)b * LEN * DIM;
    const float* wp = xpw + (size_t)k * 44 * DIM;
    int c0 = wv * 11;
    float acc[11] = {};

    for (int d0 = 0; d0 < DIM; d0 += 64) {
#pragma unroll
        for (int i = 0; i < 4; ++i) {
            int idx = (i << 8) + tid;                 // 0..1023
            int row = idx >> 4, q = idx & 15;
            int ri = maprow(k, l0 + row);
            float4 v = *(const float4*)(ub + (size_t)ri * DIM + d0 + q * 4);
            xs[row][q * 4] = v.x; xs[row][q * 4 + 1] = v.y;
            xs[row][q * 4 + 2] = v.z; xs[row][q * 4 + 3] = v.w;
        }
        __syncthreads();
#pragma unroll 4
        for (int d = 0; d < 64; ++d) {
            float u = xs[lane][d];
            const float* wd = wp + (size_t)c0 * DIM + d0 + d;
#pragma unroll
            for (int j = 0; j < 11; ++j)
                acc[j] += u * wd[(size_t)j * DIM];
        }
        __syncthreads();
    }

    // park all 44 outputs in LDS: xs[c][l]
#pragma unroll
    for (int j = 0; j < 11; ++j) xs[c0 + j][lane] = acc[j];
    __syncthreads();

    // coalesced B/C store
    float* op = bcb + ((size_t)((b * KD + k) * LEN) + l0) * 32;
#pragma unroll
    for (int i = 0; i < 8; ++i) {
        int idx = (i << 8) + tid;                     // 0..2047
        int l = idx >> 5, cc = idx & 31;
        op[idx] = xs[12 + cc][l];
    }

    // delta NHWC: per 64-d tile, compute into ds2 then coalesced write
    for (int dt = 0; dt < 6; ++dt) {
#pragma unroll
        for (int j = 0; j < 16; ++j) {
            int d = dt * 64 + wv * 16 + j;
            const float* wpd = dtw + ((size_t)(k * DIM + d)) * DTR;
            float s = dtb[k * DIM + d];
#pragma unroll
            for (int r = 0; r < DTR; ++r) s += xs[r][lane] * wpd[r];
            s = (s > 20.f) ? s : __logf(1.f + __expf(s));
            ds2[lane][wv * 16 + j] = s;
        }
        __syncthreads();
        float* dop = dlt + (((size_t)((b * KD + k) * LEN)) + l0) * DIM + dt * 64;
#pragma unroll
        for (int i = 0; i < 16; ++i) {
            int idx = (i << 8) + tid;
            int l = idx >> 6, dd = idx & 63;
            dop[(size_t)l * DIM + dd] = ds2[l][dd];
        }
        __syncthreads();
    }
}

// ---------------------------------------------------------------------------
// chunked scan phase A, NHWC. thread = d; 16 states in registers; B in LDS.
__global__ void __launch_bounds__(384) k_scan_a(
    const float* __restrict__ unh, const float* __restrict__ bcb,
    const float* __restrict__ alog, const float* __restrict__ dlt,
    float* __restrict__ hf, float* __restrict__ pA)
{
    __shared__ float bs[CHL * 16];
    int b = blockIdx.z, k = blockIdx.y, c = blockIdx.x;
    int d = threadIdx.x;
    const float* bc = bcb + ((size_t)((b * KD + k) * LEN) + c * CHL) * 32;
    for (int i = threadIdx.x; i < CHL * 4; i += 384) {
        int l = i >> 2, q = i & 3;
        ((float4*)bs)[i] = ((const float4*)bc)[l * 8 + q];
    }
    __syncthreads();

    float A[16], h[16], p[16];
    const float* ap = alog + ((size_t)(k * DIM + d)) * NST;
#pragma unroll
    for (int q = 0; q < 4; ++q) {
        float4 av = *(const float4*)(ap + q * 4);
        A[q * 4]     = -__expf(av.x); A[q * 4 + 1] = -__expf(av.y);
        A[q * 4 + 2] = -__expf(av.z); A[q * 4 + 3] = -__expf(av.w);
    }
#pragma unroll
    for (int n = 0; n < 16; ++n) { h[n] = 0.f; p[n] = 1.f; }

    const float* dp = dlt + ((size_t)((b * KD + k) * LEN) + c * CHL) * DIM + d;
    const float* ub = unh + (size_t)b * LEN * DIM + d;

    for (int l0 = 0; l0 < CHL; l0 += 4) {
        float dv[4], uu[4];
#pragma unroll
        for (int j = 0; j < 4; ++j) {
            int gl = c * CHL + l0 + j;
            dv[j] = dp[(size_t)(l0 + j) * DIM];
            uu[j] = ub[(size_t)maprow(k, gl) * DIM];
        }
#pragma unroll
        for (int j = 0; j < 4; ++j) {
            float du = dv[j] * uu[j];
            const float* bl = bs + (l0 + j) * 16;
#pragma unroll
            for (int n = 0; n < 16; ++n) {
                float dA = __expf(dv[j] * A[n]);
                h[n] = dA * h[n] + du * bl[n];
                p[n] *= dA;
            }
        }
    }
    size_t s0 = (((size_t)((b * KD + k) * DIM) + d) * NST) * NC + c;
#pragma unroll
    for (int n = 0; n < 16; ++n) { hf[s0 + (size_t)n * NC] = h[n]; pA[s0 + (size_t)n * NC] = p[n]; }
}

// phase B: serial carry combine over chunks; hf[c] overwritten with carry-IN.
__global__ void k_scan_b(float* __restrict__ hf, const float* __restrict__ pA)
{
    int s = blockIdx.x * 256 + threadIdx.x;          // 49152 states
    float* hp = hf + (size_t)s * NC;
    const float* pp = pA + (size_t)s * NC;
    float car = 0.f;
#pragma unroll
    for (int c = 0; c < NC; ++c) {
        float hfc = hp[c], pc = pp[c];
        hp[c] = car;
        car = pc * car + hfc;
    }
}

// phase C: re-run chunk from carry-in; y in-register; software-pipelined loads.
__global__ void __launch_bounds__(384) k_scan_c(
    const float* __restrict__ unh, const float* __restrict__ bcb,
    const float* __restrict__ alog, const float* __restrict__ hf,
    float* __restrict__ dlt)
{
    __shared__ float bs[CHL * 32];
    int b = blockIdx.z, k = blockIdx.y, c = blockIdx.x;
    int d = threadIdx.x;
    const float* bc = bcb + ((size_t)((b * KD + k) * LEN) + c * CHL) * 32;
    for (int i = threadIdx.x; i < CHL * 8; i += 384)
        ((float4*)bs)[i] = ((const float4*)bc)[i];
    __syncthreads();

    float A[16], h[16];
    const float* ap = alog + ((size_t)(k * DIM + d)) * NST;
#pragma unroll
    for (int q = 0; q < 4; ++q) {
        float4 av = *(const float4*)(ap + q * 4);
        A[q * 4]     = -__expf(av.x); A[q * 4 + 1] = -__expf(av.y);
        A[q * 4 + 2] = -__expf(av.z); A[q * 4 + 3] = -__expf(av.w);
    }
    size_t s0 = (((size_t)((b * KD + k) * DIM) + d) * NST) * NC + c;
#pragma unroll
    for (int n = 0; n < 16; ++n) h[n] = hf[s0 + (size_t)n * NC];

    float* dp = dlt + ((size_t)((b * KD + k) * LEN) + c * CHL) * DIM + d;
    const float* ub = unh + (size_t)b * LEN * DIM + d;

    float dv0[4], uu0[4], dv1[4], uu1[4];
#pragma unroll
    for (int j = 0; j < 4; ++j) {
        int gl = c * CHL + j;
        dv0[j] = dp[(size_t)j * DIM];
        uu0[j] = ub[(size_t)maprow(k, gl) * DIM];
    }
    for (int l0 = 0; l0 < CHL; l0 += 4) {
        if (l0 + 4 < CHL) {
#pragma unroll
            for (int j = 0; j < 4; ++j) {
                int gl = c * CHL + l0 + 4 + j;
                dv1[j] = dp[(size_t)(l0 + 4 + j) * DIM];
                uu1[j] = ub[(size_t)maprow(k, gl) * DIM];
            }
        }
        float ys[4];
#pragma unroll
        for (int j = 0; j < 4; ++j) {
            const float* bl = bs + (l0 + j) * 32;
            float du = dv0[j] * uu0[j];
            float y = 0.f;
#pragma unroll
            for (int n = 0; n < 16; ++n) {
                float dA = __expf(dv0[j] * A[n]);
                h[n] = dA * h[n] + du * bl[n];
                y += h[n] * bl[16 + n];
            }
            ys[j] = y;
        }
#pragma unroll
        for (int j = 0; j < 4; ++j) dp[(size_t)(l0 + j) * DIM] = ys[j];
#pragma unroll
        for (int j = 0; j < 4; ++j) { dv0[j] = dv1[j]; uu0[j] = uu1[j]; }
    }
}

// ---------------------------------------------------------------------------
// merge 4 directions + D*u + out-LN + silu(z) gate -> yg (B*L, 384) NHWC
__global__ void k_merge(const float* __restrict__ y4, const float* __restrict__ unh,
                        const float* __restrict__ Ds, const float* __restrict__ ong,
                        const float* __restrict__ onb, const float* __restrict__ zt,
                        float* __restrict__ yg)
{
    int lane = threadIdx.x & 63;
    int pix = (blockIdx.x << 2) + (threadIdx.x >> 6);
    int b = pix >> 12, l = pix & (LEN - 1);
    int hh = l >> 6, ww = l & 63;
    int lt = (ww << 6) + hh;
    const float* y0p = y4 + ((size_t)((b * KD + 0) * LEN) + l) * DIM;
    const float* y1p = y4 + ((size_t)((b * KD + 1) * LEN) + lt) * DIM;
    const float* y2p = y4 + ((size_t)((b * KD + 2) * LEN) + (LEN - 1 - l)) * DIM;
    const float* y3p = y4 + ((size_t)((b * KD + 3) * LEN) + (LEN - 1 - lt)) * DIM;
    const float* up  = unh + ((size_t)b * LEN + l) * DIM;
    float v[6]; float s = 0.f, ss = 0.f;
#pragma unroll
    for (int j = 0; j < 6; ++j) {
        int d = lane + (j << 6);
        float y = y0p[d] + y1p[d] + y2p[d] + y3p[d];
        float dsum = Ds[d] + Ds[DIM + d] + Ds[2 * DIM + d] + Ds[3 * DIM + d];
        y += dsum * up[d];
        v[j] = y; s += y; ss += y * y;
    }
#pragma unroll
    for (int off = 1; off < 64; off <<= 1) { s += __shfl_xor(s, off); ss += __shfl_xor(ss, off); }
    float mu = s * (1.f / 384.f);
    float var = ss * (1.f / 384.f) - mu * mu;
    float rstd = rsqrtf(var + 1e-5f);
    const float* zp = zt + (size_t)pix * DIM;
    float* op = yg + (size_t)pix * DIM;
#pragma unroll
    for (int j = 0; j < 6; ++j) {
        int d = lane + (j << 6);
        float zz = zp[d];
        float gate = zz / (1.f + __expf(-zz));
        op[d] = ((v[j] - mu) * rstd * ong[d] + onb[d]) * gate;
    }
}

// ---------------------------------------------------------------------------
extern "C" void kernel_launch(void* const* d_in, const int* in_sizes, int n_in,
                              void* d_out, int out_size, void* d_ws, size_t ws_size,
                              hipStream_t stream)
{
    const float* x    = (const float*)d_in[0];
    const float* c1w  = (const float*)d_in[1];  const float* c1b = (const float*)d_in[2];
    const float* c2w  = (const float*)d_in[3];  const float* c2b = (const float*)d_in[4];
    const float* c3w  = (const float*)d_in[5];  const float* c3b = (const float*)d_in[6];
    const float* c4w  = (const float*)d_in[7];  const float* c4b = (const float*)d_in[8];
    const float* c5w  = (const float*)d_in[9];  const float* c5b = (const float*)d_in[10];
    const float* ln1g = (const float*)d_in[11]; const float* ln1b= (const float*)d_in[12];
    const float* ipw  = (const float*)d_in[13];
    const float* dww  = (const float*)d_in[14]; const float* dwb = (const float*)d_in[15];
    const float* xpw  = (const float*)d_in[16];
    const float* dtw  = (const float*)d_in[17]; const float* dtb = (const float*)d_in[18];
    const float* alog = (const float*)d_in[19]; const float* dsv = (const float*)d_in[20];
    const float* ong  = (const float*)d_in[21]; const float* onb = (const float*)d_in[22];
    const float* opw  = (const float*)d_in[23];
    float* out = (float*)d_out;

    float* ws   = (float*)d_ws;
    float* F    = ws;                   // (B,192,L) planar       1,572,864
    float* XN   = F    + 1572864;       // (B*L,192); HF in scan; later sa planar
    float* XP   = XN   + 1572864;       // (B,384,L) planar xp    3,145,728 (PA alias)
    float* ZT   = XP   + 3145728;       // (B*L,384) z NHWC       3,145,728
    float* XCNH = ZT   + 3145728;       // (B*L,384) u NHWC       3,145,728
    float* BCB  = XCNH + 3145728;       // (B,4,L,32)             1,048,576
    float* DLT  = BCB  + 1048576;       // (B,4,L,384) delta->y   12,582,912
    float* YG   = DLT  + 12582912;      // (B*L,384) merge out    3,145,728
    // total 28,311,552 floats = 108 MB
    float* HF = XN;                     // 1,572,864 = NB*KD*DIM*NST*NC exactly
    float* PA = XP;                     // first 1,572,864 of XP (dead after k_dw)

    // stage A: dense conv block
    k_copy_x<<<dim3(2048), 256, 0, stream>>>(x, F);
    k_conv3<2><<<dim3(16, 16, NB), 256, 0, stream>>>(F, DM, 64,  c1w, c1b, F, DM, 64,  0.01f, 1);
    k_conv3<2><<<dim3(16, 16, NB), 256, 0, stream>>>(F, DM, 96,  c2w, c2b, F, DM, 96,  0.01f, 1);
    k_conv3<2><<<dim3(16, 16, NB), 256, 0, stream>>>(F, DM, 128, c3w, c3b, F, DM, 128, 0.01f, 1);
    k_conv3<2><<<dim3(16, 16, NB), 256, 0, stream>>>(F, DM, 160, c4w, c4b, F, DM, 160, 0.01f, 1);

    // stage B: VSS block
    k_ln<<<dim3(NB * LEN / 4), 256, 0, stream>>>(F, ln1g, ln1b, XN);
    k_gemm<<<dim3(LEN / 64, DIM / 64, NB), 256, 0, stream>>>(XN, DM, ipw, nullptr, XP, DIM, 0);
    k_gemm<<<dim3(LEN / 64, DIM / 64, NB), 256, 0, stream>>>(XN, DM, ipw + (size_t)DIM * DM, nullptr, ZT, DIM, 1);
    k_dw<<<dim3(HN, DIM / 64, NB), 256, 0, stream>>>(XP, dww, dwb, XCNH);
    k_xdbl_delta<<<dim3(LEN / 64, KD, NB), 256, 0, stream>>>(XCNH, xpw, dtw, dtb, BCB, DLT);
    k_scan_a<<<dim3(NC, KD, NB), 384, 0, stream>>>(XCNH, BCB, alog, DLT, HF, PA);
    k_scan_b<<<dim3(NB * KD * DIM * NST / 256), 256, 0, stream>>>(HF, PA);
    k_scan_c<<<dim3(NC, KD, NB), 384, 0, stream>>>(XCNH, BCB, alog, HF, DLT);
    k_merge<<<dim3(NB * LEN / 4), 256, 0, stream>>>(DLT, XCNH, dsv, ong, onb, ZT, YG);
    k_gemm<<<dim3(LEN / 64, DM / 64, NB), 256, 0, stream>>>(YG, DIM, opw, F, XN, DM, 0);

    // stage C: final conv
    k_conv3<4><<<dim3(16, 16, NB), 256, 0, stream>>>(XN, DM, DM, c5w, c5b, out, 64, 0, 0.f, 0);
}